// Round 1
// 170.294 us; speedup vs baseline: 1.0541x; 1.0541x over previous
//
#include <hip/hip_runtime.h>
#include <stdint.h>

// Problem constants
#define ROWS  16384   // B*T = 512*32
#define CELL  128
#define INF   512
#define RPB   16      // rows per block
#define NSTEP 32

typedef _Float16 f16x8 __attribute__((ext_vector_type(8)));
typedef _Float16 f16x4 __attribute__((ext_vector_type(4)));
typedef float    f32x4 __attribute__((ext_vector_type(4)));

#define MFMA16(a, b, c) __builtin_amdgcn_mfma_f32_16x16x32_f16((a), (b), (c), 0, 0, 0)

// ws layout (f16 elems), all in 16x16x32 B-fragment order:
//   A_sw[g]  at g*16384          (g=0..3: Wf,Wi1,Wi2,Wo rows 0..127, cell part)
//   Xw_sw[g] at 65536 + g*65536  (rows 128..639, x part)
//   Wc_sw    at 327680
// frag addr: ((ks*8 + nb)*64 + lane)*8 + j  <->
//   W[ks*32 + ((lane>>4)<<3) + j][nb*16 + (lane&15)]
#define AOFF  0
#define XOFF  65536
#define WCOFF 327680
#define WSTOT 344064

__device__ __forceinline__ unsigned short f2h_bits(float f) {
  _Float16 h = (_Float16)f;
  return *(unsigned short*)&h;
}
__device__ __forceinline__ float sig_f(float z) {
  return __builtin_amdgcn_rcpf(1.f + __expf(-z));
}
__device__ __forceinline__ float tanh_f(float z) {
  return 1.f - 2.f * __builtin_amdgcn_rcpf(__expf(2.f * z) + 1.f);
}

// Source-indexed: consecutive threads read consecutive W columns (coalesced);
// the 2B frag-order writes scatter, but stores don't stall.
__global__ __launch_bounds__(256) void prep_kernel(
    const float* __restrict__ Wf, const float* __restrict__ Wi1,
    const float* __restrict__ Wi2, const float* __restrict__ Wo,
    const float* __restrict__ Wc, unsigned short* __restrict__ ws) {
  int id = blockIdx.x * blockDim.x + threadIdx.x;
  if (id >= WSTOT) return;
  const float* Wg[4] = {Wf, Wi1, Wi2, Wo};
  float v;
  int k, n, base;
  if (id < XOFF) {                       // recurrent (cell) part, k = 0..127
    int g = id >> 14, r = id & 16383;
    k = r >> 7; n = r & 127;
    v = Wg[g][k * CELL + n];
    base = g * 16384;
  } else if (id < WCOFF) {               // x part, k = 0..511 -> W row 128+k
    int t = id - XOFF;
    int g = t >> 16, r = t & 65535;
    k = r >> 7; n = r & 127;
    v = Wg[g][(CELL + k) * CELL + n];
    base = XOFF + g * 65536;
  } else {                               // Wc [128][128]
    int r = id - WCOFF;
    k = r >> 7; n = r & 127;
    v = Wc[k * CELL + n];
    base = WCOFF;
  }
  int ks = k >> 5, kk = k & 31;
  int lane = ((kk >> 3) << 4) | (n & 15);
  int j = kk & 7, nb = n >> 4;
  ws[base + ((ks * 8 + nb) * 64 + lane) * 8 + j] = f2h_bits(v);
}

// 16 rows/block, 8 waves (512 thr), each wave owns a 16x16 output tile
// (cols [w*16, w*16+16)). 16x16x32 MFMA => K=128 is 4 k-steps: recurrent
// weights (3 gates) = 48 VGPRs/wave, u (all 4 gates) = 16 VGPRs, acc = 12.
// Target <=128 VGPR -> 4 waves/SIMD -> 16 waves/CU (2x the previous 32-row
// 32x32-tile version, which was capped at 8 waves/CU by the grid).
__global__ __launch_bounds__(512, 4) void lstm_kernel(
    const float* __restrict__ x,
    const float* __restrict__ bf_, const float* __restrict__ bi1,
    const float* __restrict__ bi2, const float* __restrict__ bo,
    const float* __restrict__ bc,
    const unsigned short* __restrict__ ws, float* __restrict__ out) {

  __shared__ _Float16 cF[2][16][136];        // 8704 B, double-buffered c
  __shared__ union {
    _Float16 xs[16][520];                    // 16640 B, x staging (whole 512)
    struct {
      float    s[16][132];                   // 8448 B, softmax scores
      _Float16 o[16][136];                   // 4352 B, o-gate activations
    } ep;                                    // 12800 B
  } uS;                                      // total LDS: 25344 B

  const int tid  = threadIdx.x;
  const int lane = tid & 63;
  const int w    = tid >> 6;     // wave 0..7, owns cols [w*16, w*16+16)
  const int n16  = lane & 15;
  const int g4   = lane >> 4;    // 0..3
  const int col  = w * 16 + n16; // this lane's output column
  const int r0   = blockIdx.x * RPB;

  const _Float16* Aw  = (const _Float16*)ws + AOFF;
  const _Float16* Xw  = (const _Float16*)ws + XOFF;
  const _Float16* Wcw = (const _Float16*)ws + WCOFF;

  // ---------------- stage x (16 rows x 512 f32 -> f16) --------------------
  {
    const float* xb = x + (size_t)r0 * INF;
#pragma unroll
    for (int i = 0; i < 4; ++i) {
      int flat = tid + i * 512;            // 2048 = 16 rows * 128 float4
      int row = flat >> 7, c4 = flat & 127;
      const float4 v = ((const float4*)(xb + (size_t)row * INF))[c4];
      f16x4 h = {(_Float16)v.x, (_Float16)v.y, (_Float16)v.z, (_Float16)v.w};
      *(f16x4*)&uS.xs[row][c4 * 4] = h;
    }
  }
  __syncthreads();

  // ---------------- precompute u_g = x @ Wg[128:,:] + b -------------------
  f32x4 u[4];
#pragma unroll
  for (int g = 0; g < 4; ++g)
#pragma unroll
    for (int i = 0; i < 4; ++i) u[g][i] = 0.f;

#pragma unroll 4
  for (int ks = 0; ks < 16; ++ks) {
    f16x8 a = *(const f16x8*)&uS.xs[n16][ks * 32 + g4 * 8];
#pragma unroll
    for (int g = 0; g < 4; ++g) {
      f16x8 b = *(const f16x8*)(Xw + g * 65536 + ((ks * 8 + w) * 64 + lane) * 8);
      u[g] = MFMA16(a, b, u[g]);
    }
  }
  {
    float b0 = bf_[col], b1 = bi1[col], b2 = bi2[col], b3 = bo[col];
#pragma unroll
    for (int i = 0; i < 4; ++i) {
      u[0][i] += b0; u[1][i] += b1; u[2][i] += b2; u[3][i] += b3;
    }
  }

  // ---------------- recurrent-gate weights -> registers -------------------
  f16x8 wr[3][4];   // [gate f,i1,i2][ks] -> 48 VGPRs
#pragma unroll
  for (int g = 0; g < 3; ++g)
#pragma unroll
    for (int ks = 0; ks < 4; ++ks)
      wr[g][ks] = *(const f16x8*)(Aw + g * 16384 + ((ks * 8 + w) * 64 + lane) * 8);

  // ---------------- step 0: c_prev = 0 => z = u ---------------------------
  f32x4 cr;
#pragma unroll
  for (int i = 0; i < 4; ++i) {
    float c0 = sig_f(u[1][i]) * tanh_f(u[2][i]);
    cr[i] = c0;
    cF[0][g4 * 4 + i][col] = (_Float16)c0;
  }
  __syncthreads();

  // ---------------- recurrence: steps 1..30 -------------------------------
#pragma unroll 1
  for (int t = 1; t < NSTEP - 1; ++t) {
    const int rb = (t + 1) & 1, wb = t & 1;
    f16x8 a[4];
#pragma unroll
    for (int ks = 0; ks < 4; ++ks)
      a[ks] = *(const f16x8*)&cF[rb][n16][ks * 32 + g4 * 8];
    f32x4 zf = u[0], zi1 = u[1], zi2 = u[2];
#pragma unroll
    for (int ks = 0; ks < 4; ++ks) {
      zf  = MFMA16(a[ks], wr[0][ks], zf);
      zi1 = MFMA16(a[ks], wr[1][ks], zi1);
      zi2 = MFMA16(a[ks], wr[2][ks], zi2);
    }
#pragma unroll
    for (int i = 0; i < 4; ++i) {
      float fg = sig_f(zf[i]);
      float ig = sig_f(zi1[i]);
      float gg = tanh_f(zi2[i]);
      float cn = fmaf(cr[i], fg, ig * gg);
      cr[i] = cn;
      cF[wb][g4 * 4 + i][col] = (_Float16)cn;
    }
    __syncthreads();
  }

  // ---------------- final step (t=31): + o-gate ---------------------------
  {
    // reads cF[0] (written at t=30)
    f16x8 a[4];
#pragma unroll
    for (int ks = 0; ks < 4; ++ks)
      a[ks] = *(const f16x8*)&cF[0][n16][ks * 32 + g4 * 8];
    f32x4 zf = u[0], zi1 = u[1], zi2 = u[2], zo = u[3];
#pragma unroll
    for (int ks = 0; ks < 4; ++ks) {
      f16x8 bo_frag = *(const f16x8*)(Aw + 3 * 16384 + ((ks * 8 + w) * 64 + lane) * 8);
      zf  = MFMA16(a[ks], wr[0][ks], zf);
      zi1 = MFMA16(a[ks], wr[1][ks], zi1);
      zi2 = MFMA16(a[ks], wr[2][ks], zi2);
      zo  = MFMA16(a[ks], bo_frag, zo);
    }
#pragma unroll
    for (int i = 0; i < 4; ++i) {
      float fg = sig_f(zf[i]);
      float ig = sig_f(zi1[i]);
      float gg = tanh_f(zi2[i]);
      float cn = fmaf(cr[i], fg, ig * gg);
      cr[i] = cn;
      float ov = sig_f(zo[i]) * tanh_f(cn);
      uS.ep.o[g4 * 4 + i][col] = (_Float16)ov;   // xs dead; o-region safe
    }
    __syncthreads();
  }

  // ---------------- epilogue: s = o @ Wc + bc, softmax --------------------
  {
    f32x4 sacc;
#pragma unroll
    for (int i = 0; i < 4; ++i) sacc[i] = 0.f;
#pragma unroll
    for (int ks = 0; ks < 4; ++ks) {
      f16x8 a = *(const f16x8*)&uS.ep.o[n16][ks * 32 + g4 * 8];
      f16x8 b = *(const f16x8*)(Wcw + ((ks * 8 + w) * 64 + lane) * 8);
      sacc = MFMA16(a, b, sacc);
    }
    float bv = bc[col];
#pragma unroll
    for (int i = 0; i < 4; ++i)
      uS.ep.s[g4 * 4 + i][col] = sacc[i] + bv;
    __syncthreads();

    // wave w reduces rows w*2, w*2+1; lane covers cols {lane, lane+64}
#pragma unroll
    for (int rr = 0; rr < 2; ++rr) {
      int r = w * 2 + rr;
      float v0 = uS.ep.s[r][lane];
      float v1 = uS.ep.s[r][lane + 64];
      float m = fmaxf(v0, v1);
#pragma unroll
      for (int off = 32; off; off >>= 1) m = fmaxf(m, __shfl_xor(m, off, 64));
      float e0 = __expf(v0 - m), e1 = __expf(v1 - m);
      float sm = e0 + e1;
#pragma unroll
      for (int off = 32; off; off >>= 1) sm += __shfl_xor(sm, off, 64);
      float inv = __builtin_amdgcn_rcpf(sm);
      size_t base = (size_t)(r0 + r) * 128;
      out[base + lane]      = e0 * inv;
      out[base + lane + 64] = e1 * inv;
    }

    // final c (output 1) at offset ROWS*128
#pragma unroll
    for (int i = 0; i < 4; ++i)
      out[(size_t)ROWS * 128 + (size_t)(r0 + g4 * 4 + i) * 128 + col] = cr[i];
  }
}

extern "C" void kernel_launch(void* const* d_in, const int* in_sizes, int n_in,
                              void* d_out, int out_size, void* d_ws, size_t ws_size,
                              hipStream_t stream) {
  const float* x   = (const float*)d_in[0];
  const float* Wf  = (const float*)d_in[1];
  const float* bf_ = (const float*)d_in[2];
  const float* Wi1 = (const float*)d_in[3];
  const float* bi1 = (const float*)d_in[4];
  const float* Wi2 = (const float*)d_in[5];
  const float* bi2 = (const float*)d_in[6];
  const float* Wo  = (const float*)d_in[7];
  const float* bo  = (const float*)d_in[8];
  const float* Wc  = (const float*)d_in[9];
  const float* bc  = (const float*)d_in[10];
  unsigned short* ws = (unsigned short*)d_ws;
  float* out = (float*)d_out;

  hipLaunchKernelGGL(prep_kernel, dim3((WSTOT + 255) / 256), dim3(256), 0, stream,
                     Wf, Wi1, Wi2, Wo, Wc, ws);
  hipLaunchKernelGGL(lstm_kernel, dim3(ROWS / RPB), dim3(512), 0, stream,
                     x, bf_, bi1, bi2, bo, bc, ws, out);
}

// Round 2
// 168.474 us; speedup vs baseline: 1.0655x; 1.0108x over previous
//
#include <hip/hip_runtime.h>
#include <stdint.h>

// Problem constants
#define ROWS  16384   // B*T = 512*32
#define CELL  128
#define INF   512
#define RPB   16      // rows per block
#define NSTEP 32

typedef _Float16 f16x8 __attribute__((ext_vector_type(8)));
typedef _Float16 f16x4 __attribute__((ext_vector_type(4)));
typedef float    f32x4 __attribute__((ext_vector_type(4)));

#define MFMA16(a, b, c) __builtin_amdgcn_mfma_f32_16x16x32_f16((a), (b), (c), 0, 0, 0)

// ws layout (f16 elems), all in 16x16x32 fragment order (A and B frag layouts
// are identical on gfx950: element dim = lane&15, k = (lane>>4)*8 + j):
//   A_sw[g]  at g*16384          (g=0..3: Wf,Wi1,Wi2,Wo rows 0..127, cell part)
//   Xw_sw[g] at 65536 + g*65536  (rows 128..639, x part)
//   Wc_sw    at 327680
// frag addr: ((ks*8 + nb)*64 + lane)*8 + j  <->
//   W[ks*32 + ((lane>>4)<<3) + j][nb*16 + (lane&15)]
// Weights are PRE-SCALED: Wf,Wi1,Wo by log2(e); Wi2 by 2*log2(e); Wc by 1.
// Gates then use exp2 directly (no per-element log2e multiply).
#define AOFF  0
#define XOFF  65536
#define WCOFF 327680
#define WSTOT 344064

#define LOG2E  1.44269504f
#define LOG2E2 2.88539008f

__device__ __forceinline__ unsigned short f2h_bits(float f) {
  _Float16 h = (_Float16)f;
  return *(unsigned short*)&h;
}
// z pre-scaled by log2e: sigmoid(z_real) = 1/(1+2^(-z))
__device__ __forceinline__ float sig2(float z) {
  return __builtin_amdgcn_rcpf(1.f + __builtin_amdgcn_exp2f(-z));
}
// z pre-scaled by 2*log2e: tanh(z_real) = 1 - 2/(2^z + 1)
__device__ __forceinline__ float tanh2(float z) {
  return 1.f - 2.f * __builtin_amdgcn_rcpf(__builtin_amdgcn_exp2f(z) + 1.f);
}

// Source-indexed: consecutive threads read consecutive W columns (coalesced);
// the 2B frag-order writes scatter, but stores don't stall.
__global__ __launch_bounds__(256) void prep_kernel(
    const float* __restrict__ Wf, const float* __restrict__ Wi1,
    const float* __restrict__ Wi2, const float* __restrict__ Wo,
    const float* __restrict__ Wc, unsigned short* __restrict__ ws) {
  int id = blockIdx.x * blockDim.x + threadIdx.x;
  if (id >= WSTOT) return;
  const float* Wg[4] = {Wf, Wi1, Wi2, Wo};
  const float scl[4] = {LOG2E, LOG2E, LOG2E2, LOG2E};
  float v;
  int k, n, base;
  if (id < XOFF) {                       // recurrent (cell) part, k = 0..127
    int g = id >> 14, r = id & 16383;
    k = r >> 7; n = r & 127;
    v = Wg[g][k * CELL + n] * scl[g];
    base = g * 16384;
  } else if (id < WCOFF) {               // x part, k = 0..511 -> W row 128+k
    int t = id - XOFF;
    int g = t >> 16, r = t & 65535;
    k = r >> 7; n = r & 127;
    v = Wg[g][(CELL + k) * CELL + n] * scl[g];
    base = XOFF + g * 65536;
  } else {                               // Wc [128][128], unscaled
    int r = id - WCOFF;
    k = r >> 7; n = r & 127;
    v = Wc[k * CELL + n];
    base = WCOFF;
  }
  int ks = k >> 5, kk = k & 31;
  int lane = ((kk >> 3) << 4) | (n & 15);
  int j = kk & 7, nb = n >> 4;
  ws[base + ((ks * 8 + nb) * 64 + lane) * 8 + j] = f2h_bits(v);
}

// 16 rows/block, 8 waves (512 thr). MFMA operands SWAPPED vs the classic
// orientation: z = mfma(W_frag, act_frag) so the C/D mapping becomes
// batch = lane&15, col = w*16 + (lane>>4)*4 + reg. Each lane owns 4
// CONSECUTIVE columns of ONE row => cF update is a single ds_write_b64
// (was 4 scalar b16 stores, the bank-conflict source), and all epilogue
// stores become vector b64/float4.
__global__ __launch_bounds__(512, 4) void lstm_kernel(
    const float* __restrict__ x,
    const float* __restrict__ bf_, const float* __restrict__ bi1,
    const float* __restrict__ bi2, const float* __restrict__ bo,
    const float* __restrict__ bc,
    const unsigned short* __restrict__ ws, float* __restrict__ out) {

  __shared__ _Float16 cF[2][16][136];        // 8704 B, double-buffered c
  __shared__ union {
    _Float16 xs[16][520];                    // 16640 B, x staging (whole 512)
    struct {
      float    s[16][132];                   // 8448 B, softmax scores
      _Float16 o[16][136];                   // 4352 B, o-gate activations
    } ep;                                    // 12800 B
  } uS;                                      // total LDS: 25344 B

  const int tid  = threadIdx.x;
  const int lane = tid & 63;
  const int w    = tid >> 6;     // wave 0..7
  const int n16  = lane & 15;    // this lane's batch row (output mapping)
  const int g4   = lane >> 4;    // 0..3
  const int col0 = w * 16 + g4 * 4;  // first of this lane's 4 output columns
  const int r0   = blockIdx.x * RPB;

  const _Float16* Aw  = (const _Float16*)ws + AOFF;
  const _Float16* Xw  = (const _Float16*)ws + XOFF;
  const _Float16* Wcw = (const _Float16*)ws + WCOFF;

  // ---------------- stage x (16 rows x 512 f32 -> f16) --------------------
  {
    const float* xb = x + (size_t)r0 * INF;
#pragma unroll
    for (int i = 0; i < 4; ++i) {
      int flat = tid + i * 512;            // 2048 = 16 rows * 128 float4
      int row = flat >> 7, c4 = flat & 127;
      const float4 v = ((const float4*)(xb + (size_t)row * INF))[c4];
      f16x4 h = {(_Float16)v.x, (_Float16)v.y, (_Float16)v.z, (_Float16)v.w};
      *(f16x4*)&uS.xs[row][c4 * 4] = h;
    }
  }
  __syncthreads();

  // ---------------- precompute u_g = x @ Wg[128:,:] + b -------------------
  f32x4 u[4];
#pragma unroll
  for (int g = 0; g < 4; ++g)
#pragma unroll
    for (int i = 0; i < 4; ++i) u[g][i] = 0.f;

#pragma unroll 4
  for (int ks = 0; ks < 16; ++ks) {
    // B-frag of x^T: lane reads x[batch=n16][xcol = 32ks + g4*8 + j]
    f16x8 a = *(const f16x8*)&uS.xs[n16][ks * 32 + g4 * 8];
#pragma unroll
    for (int g = 0; g < 4; ++g) {
      f16x8 b = *(const f16x8*)(Xw + g * 65536 + ((ks * 8 + w) * 64 + lane) * 8);
      u[g] = MFMA16(b, a, u[g]);   // swapped: weights as A
    }
  }
  {
    // biases: 4 consecutive cols per lane -> vector loads; scale by log2e
    f32x4 b0 = *(const f32x4*)&bf_[col0];
    f32x4 b1 = *(const f32x4*)&bi1[col0];
    f32x4 b2 = *(const f32x4*)&bi2[col0];
    f32x4 b3 = *(const f32x4*)&bo[col0];
#pragma unroll
    for (int i = 0; i < 4; ++i) {
      u[0][i] = fmaf(b0[i], LOG2E,  u[0][i]);
      u[1][i] = fmaf(b1[i], LOG2E,  u[1][i]);
      u[2][i] = fmaf(b2[i], LOG2E2, u[2][i]);
      u[3][i] = fmaf(b3[i], LOG2E,  u[3][i]);
    }
  }

  // ---------------- recurrent-gate weights -> registers -------------------
  f16x8 wr[3][4];   // [gate f,i1,i2][ks] -> 48 VGPRs
#pragma unroll
  for (int g = 0; g < 3; ++g)
#pragma unroll
    for (int ks = 0; ks < 4; ++ks)
      wr[g][ks] = *(const f16x8*)(Aw + g * 16384 + ((ks * 8 + w) * 64 + lane) * 8);

  // ---------------- step 0: c_prev = 0 => z = u ---------------------------
  f32x4 cr;
  {
    f16x4 hv;
#pragma unroll
    for (int i = 0; i < 4; ++i) {
      float c0 = sig2(u[1][i]) * tanh2(u[2][i]);
      cr[i] = c0;
      hv[i] = (_Float16)c0;
    }
    *(f16x4*)&cF[0][n16][col0] = hv;       // single b64 store
  }
  __syncthreads();

  // ---------------- recurrence: steps 1..30 -------------------------------
#pragma unroll 1
  for (int t = 1; t < NSTEP - 1; ++t) {
    const int rb = (t + 1) & 1, wb = t & 1;
    f16x8 a[4];
#pragma unroll
    for (int ks = 0; ks < 4; ++ks)   // B-frag of c^T: c[batch=n16][8 cols]
      a[ks] = *(const f16x8*)&cF[rb][n16][ks * 32 + g4 * 8];
    f32x4 zf = u[0], zi1 = u[1], zi2 = u[2];
#pragma unroll
    for (int ks = 0; ks < 4; ++ks) {
      zf  = MFMA16(wr[0][ks], a[ks], zf);
      zi1 = MFMA16(wr[1][ks], a[ks], zi1);
      zi2 = MFMA16(wr[2][ks], a[ks], zi2);
    }
    f16x4 hv;
#pragma unroll
    for (int i = 0; i < 4; ++i) {
      float fg = sig2(zf[i]);
      float ig = sig2(zi1[i]);
      float gg = tanh2(zi2[i]);
      float cn = fmaf(cr[i], fg, ig * gg);
      cr[i] = cn;
      hv[i] = (_Float16)cn;
    }
    *(f16x4*)&cF[wb][n16][col0] = hv;      // single b64 store
    __syncthreads();
  }

  // ---------------- final step (t=31): + o-gate ---------------------------
  {
    // reads cF[0] (written at t=30)
    f16x8 a[4];
#pragma unroll
    for (int ks = 0; ks < 4; ++ks)
      a[ks] = *(const f16x8*)&cF[0][n16][ks * 32 + g4 * 8];
    f32x4 zf = u[0], zi1 = u[1], zi2 = u[2], zo = u[3];
#pragma unroll
    for (int ks = 0; ks < 4; ++ks) {
      f16x8 bo_frag = *(const f16x8*)(Aw + 3 * 16384 + ((ks * 8 + w) * 64 + lane) * 8);
      zf  = MFMA16(wr[0][ks], a[ks], zf);
      zi1 = MFMA16(wr[1][ks], a[ks], zi1);
      zi2 = MFMA16(wr[2][ks], a[ks], zi2);
      zo  = MFMA16(bo_frag,  a[ks], zo);
    }
    f16x4 hv;
#pragma unroll
    for (int i = 0; i < 4; ++i) {
      float fg = sig2(zf[i]);
      float ig = sig2(zi1[i]);
      float gg = tanh2(zi2[i]);
      float cn = fmaf(cr[i], fg, ig * gg);
      cr[i] = cn;
      float ov = sig2(zo[i]) * tanh2(cn * LOG2E2);  // cn unscaled
      hv[i] = (_Float16)ov;
    }
    __syncthreads();   // all reads of cF/xs done; uS.ep becomes live
    *(f16x4*)&uS.ep.o[n16][col0] = hv;
    __syncthreads();
  }

  // ---------------- epilogue: s = o @ Wc + bc, softmax --------------------
  {
    f32x4 sacc;
#pragma unroll
    for (int i = 0; i < 4; ++i) sacc[i] = 0.f;
#pragma unroll
    for (int ks = 0; ks < 4; ++ks) {
      f16x8 a = *(const f16x8*)&uS.ep.o[n16][ks * 32 + g4 * 8];
      f16x8 b = *(const f16x8*)(Wcw + ((ks * 8 + w) * 64 + lane) * 8);
      sacc = MFMA16(b, a, sacc);
    }
    f32x4 bcv = *(const f32x4*)&bc[col0];
#pragma unroll
    for (int i = 0; i < 4; ++i) sacc[i] += bcv[i];
    *(f32x4*)&uS.ep.s[n16][col0] = sacc;   // single b128 store
    __syncthreads();

    // wave w reduces rows w*2, w*2+1; lane covers cols {lane, lane+64}
#pragma unroll
    for (int rr = 0; rr < 2; ++rr) {
      int r = w * 2 + rr;
      float v0 = uS.ep.s[r][lane];
      float v1 = uS.ep.s[r][lane + 64];
      float m = fmaxf(v0, v1);
#pragma unroll
      for (int off = 32; off; off >>= 1) m = fmaxf(m, __shfl_xor(m, off, 64));
      float e0 = __expf(v0 - m), e1 = __expf(v1 - m);
      float sm = e0 + e1;
#pragma unroll
      for (int off = 32; off; off >>= 1) sm += __shfl_xor(sm, off, 64);
      float inv = __builtin_amdgcn_rcpf(sm);
      size_t base = (size_t)(r0 + r) * 128;
      out[base + lane]      = e0 * inv;
      out[base + lane + 64] = e1 * inv;
    }

    // final c (output 1) at offset ROWS*128 — float4 store per lane
    *(f32x4*)&out[(size_t)ROWS * 128 + (size_t)(r0 + n16) * 128 + col0] = cr;
  }
}

extern "C" void kernel_launch(void* const* d_in, const int* in_sizes, int n_in,
                              void* d_out, int out_size, void* d_ws, size_t ws_size,
                              hipStream_t stream) {
  const float* x   = (const float*)d_in[0];
  const float* Wf  = (const float*)d_in[1];
  const float* bf_ = (const float*)d_in[2];
  const float* Wi1 = (const float*)d_in[3];
  const float* bi1 = (const float*)d_in[4];
  const float* Wi2 = (const float*)d_in[5];
  const float* bi2 = (const float*)d_in[6];
  const float* Wo  = (const float*)d_in[7];
  const float* bo  = (const float*)d_in[8];
  const float* Wc  = (const float*)d_in[9];
  const float* bc  = (const float*)d_in[10];
  unsigned short* ws = (unsigned short*)d_ws;
  float* out = (float*)d_out;

  hipLaunchKernelGGL(prep_kernel, dim3((WSTOT + 255) / 256), dim3(256), 0, stream,
                     Wf, Wi1, Wi2, Wo, Wc, ws);
  hipLaunchKernelGGL(lstm_kernel, dim3(ROWS / RPB), dim3(512), 0, stream,
                     x, bf_, bi1, bi2, bo, bc, ws, out);
}